// Round 14
// baseline (127.631 us; speedup 1.0000x reference)
//
#include <hip/hip_runtime.h>
#include <hip/hip_bf16.h>

#define N_NODES 50000
#define N_EDGES 640000
#define D 128
#define OUT0_ELEMS (N_NODES * D)
#define SCAN_BLOCKS ((N_NODES + 255) / 256)   // 196

// gather_chunk geometry: 4 column-chunks of 32 cols; 64 nodes/block.
#define GB_NODES 64
#define GB_BLOCKS_PER_CHUNK ((N_NODES + GB_NODES - 1) / GB_NODES)   // 782

typedef __attribute__((ext_vector_type(8))) short short8v;   // 8 bf16
typedef __attribute__((ext_vector_type(4))) short short4v;   // 4 bf16
typedef __attribute__((ext_vector_type(4))) float f32x4;

static __device__ __forceinline__ unsigned short f2bf(float x) {
  __hip_bfloat16 b = __float2bfloat16(x);   // RNE
  return *reinterpret_cast<unsigned short*>(&b);
}
static __device__ __forceinline__ float bf2f(unsigned short u) {
  unsigned x = ((unsigned)u) << 16;
  return __builtin_bit_cast(float, x);
}
// Edge record: (bf16(w) << 16) | src   (src < 50000 < 2^16)
static __device__ __forceinline__ unsigned pack_edge(int s, float wv) {
  return ((unsigned)f2bf(wv) << 16) | (unsigned)s;
}

// ---------------------------------------------------------------------------
// conv_all: nfeat f32->bf16 into the chunked layout nf16t[4][N][32],
// W1/W2 -> bf16, zero cnt.  3125 blocks x 256 thr x 8 elems.  (proven)
// ---------------------------------------------------------------------------
__global__ __launch_bounds__(256) void conv_all(
    const float* __restrict__ nfeat, const float* __restrict__ W1,
    const float* __restrict__ W2, unsigned short* __restrict__ nf16t,
    unsigned short* __restrict__ wc, int* __restrict__ cnt) {
  int i = blockIdx.x * 256 + threadIdx.x;
  int base = i * 8;
  float4 a = *(const float4*)(nfeat + base);
  float4 b = *(const float4*)(nfeat + base + 4);
  short8v o;
  o[0] = (short)f2bf(a.x); o[1] = (short)f2bf(a.y);
  o[2] = (short)f2bf(a.z); o[3] = (short)f2bf(a.w);
  o[4] = (short)f2bf(b.x); o[5] = (short)f2bf(b.y);
  o[6] = (short)f2bf(b.z); o[7] = (short)f2bf(b.w);
  // cols [col0, col0+8) all land in chunk col0>>5 (col0 is 8-aligned)
  {
    int node = base >> 7;
    int col0 = base & 127;
    int c = col0 >> 5;
    int within = col0 & 31;
    *(short8v*)(nf16t + ((size_t)c * N_NODES + node) * 32 + within) = o;
  }
  if (i < D * D) {
    wc[i] = f2bf(W1[i]);
    wc[D * D + i] = f2bf(W2[i]);
  }
  if (i < N_NODES) cnt[i] = 0;
}

// ---------------------------------------------------------------------------
// hist4: FIRE-AND-FORGET histogram (result unused -> global_atomic_add
// without return; waves stream instead of stalling on the return chain).
// The per-edge rank is regenerated later in fill_cur.  4 edges/thread.
// ---------------------------------------------------------------------------
__global__ __launch_bounds__(256) void hist4(
    const int* __restrict__ dst, int* __restrict__ cnt) {
  int t = blockIdx.x * 256 + threadIdx.x;
  int e = t * 4;
  if (e >= N_EDGES) return;
  int4 d4 = *(const int4*)(dst + e);
  atomicAdd(&cnt[d4.x], 1);
  atomicAdd(&cnt[d4.y], 1);
  atomicAdd(&cnt[d4.z], 1);
  atomicAdd(&cnt[d4.w], 1);
}

// ---------------------------------------------------------------------------
// scan_block: per-block exclusive scan into offs (block-local), totals into
// bsums, and RE-ZERO cnt so fill_cur can reuse it as its rank cursor.
// ---------------------------------------------------------------------------
__global__ __launch_bounds__(256) void scan_block(
    const int* __restrict__ cnt_in, int* __restrict__ cnt_zero,
    int* __restrict__ offs, int* __restrict__ bsums) {
  __shared__ int sdata[256];
  int t = threadIdx.x;
  int i = blockIdx.x * 256 + t;
  int v = (i < N_NODES) ? cnt_in[i] : 0;
  sdata[t] = v;
  __syncthreads();
#pragma unroll
  for (int off = 1; off < 256; off <<= 1) {
    int x = (t >= off) ? sdata[t - off] : 0;
    __syncthreads();
    sdata[t] += x;
    __syncthreads();
  }
  if (i < N_NODES) {
    offs[i] = sdata[t] - v;   // block-local exclusive
    cnt_zero[i] = 0;          // reset cursor for fill_cur
  }
  if (t == 255) bsums[blockIdx.x] = sdata[t];
}

// Inclusive LDS scan of bsums (196 entries); prefix(b) = b ? sincl[b-1] : 0.
static __device__ __forceinline__ void scan_bsums_lds(
    const int* __restrict__ bsums, int* sincl) {
  int t = threadIdx.x;
  int v = (t < SCAN_BLOCKS) ? bsums[t] : 0;
  sincl[t] = v;
  __syncthreads();
#pragma unroll
  for (int off = 1; off < 256; off <<= 1) {
    int x = (t >= off) ? sincl[t - off] : 0;
    __syncthreads();
    sincl[t] += x;
    __syncthreads();
  }
}

// ---------------------------------------------------------------------------
// fill_cur: scatter of packed 4B records; bucket base computed on the fly
// (offs local + bsums prefix), intra-bucket rank from atomicAdd on the
// re-zeroed cnt.  Replaces fill4+rank: -5.1MB traffic, hist loses its
// return-stall.  4 independent atomics/thread hide the return latency.
// ---------------------------------------------------------------------------
__global__ __launch_bounds__(256) void fill_cur(
    const int* __restrict__ src, const int* __restrict__ dst,
    const float* __restrict__ w, int* __restrict__ cnt,
    const int* __restrict__ offs, const int* __restrict__ bsums,
    unsigned* __restrict__ es) {
  __shared__ int sincl[256];
  scan_bsums_lds(bsums, sincl);
  int t = blockIdx.x * 256 + threadIdx.x;
  int e = t * 4;
  if (e >= N_EDGES) return;
  int4 d4 = *(const int4*)(dst + e);
  int4 s4 = *(const int4*)(src + e);
  float4 w4 = *(const float4*)(w + e);
  int b0 = offs[d4.x] + ((d4.x >> 8) ? sincl[(d4.x >> 8) - 1] : 0);
  int b1 = offs[d4.y] + ((d4.y >> 8) ? sincl[(d4.y >> 8) - 1] : 0);
  int b2 = offs[d4.z] + ((d4.z >> 8) ? sincl[(d4.z >> 8) - 1] : 0);
  int b3 = offs[d4.w] + ((d4.w >> 8) ? sincl[(d4.w >> 8) - 1] : 0);
  int r0 = atomicAdd(&cnt[d4.x], 1);
  int r1 = atomicAdd(&cnt[d4.y], 1);
  int r2 = atomicAdd(&cnt[d4.z], 1);
  int r3 = atomicAdd(&cnt[d4.w], 1);
  es[b0 + r0] = pack_edge(s4.x, w4.x);
  es[b1 + r1] = pack_edge(s4.y, w4.y);
  es[b2 + r2] = pack_edge(s4.z, w4.z);
  es[b3 + r3] = pack_edge(s4.w, w4.w);
}

// ---------------------------------------------------------------------------
// gather_chunk: XCD-L2-resident gather (round-13 proven form).  chunk =
// blockIdx&3; plain vectorizable es loads.
// ---------------------------------------------------------------------------
__global__ __launch_bounds__(256) void gather_chunk(
    const unsigned short* __restrict__ nf16t, const int* __restrict__ offs,
    const int* __restrict__ bsums, const unsigned* __restrict__ es,
    float* __restrict__ hn) {
  __shared__ int sincl[256];
  scan_bsums_lds(bsums, sincl);

  const int c = blockIdx.x & 3;
  const int g = blockIdx.x >> 2;
  const int tid = threadIdx.x;
  const int node = g * GB_NODES + (tid >> 2);
  if (node >= N_NODES) return;
  const int q = tid & 3;

  const unsigned short* chunk = nf16t + (size_t)c * N_NODES * 32;

  int beg = offs[node] + ((node >> 8) ? sincl[(node >> 8) - 1] : 0);
  int end;
  {
    int n1 = node + 1;
    end = (n1 == N_NODES) ? N_EDGES
                          : offs[n1] + ((n1 >> 8) ? sincl[(n1 >> 8) - 1] : 0);
  }

  float acc[8];
#pragma unroll
  for (int j = 0; j < 8; ++j) acc[j] = 0.f;

  int k = beg;
  for (; k + 3 < end; k += 4) {
    unsigned r0 = es[k], r1 = es[k + 1], r2 = es[k + 2], r3 = es[k + 3];
    short8v v0 = *(const short8v*)(chunk + (size_t)(r0 & 0xFFFF) * 32 + q * 8);
    short8v v1 = *(const short8v*)(chunk + (size_t)(r1 & 0xFFFF) * 32 + q * 8);
    short8v v2 = *(const short8v*)(chunk + (size_t)(r2 & 0xFFFF) * 32 + q * 8);
    short8v v3 = *(const short8v*)(chunk + (size_t)(r3 & 0xFFFF) * 32 + q * 8);
    float w0 = bf2f((unsigned short)(r0 >> 16));
    float w1 = bf2f((unsigned short)(r1 >> 16));
    float w2 = bf2f((unsigned short)(r2 >> 16));
    float w3 = bf2f((unsigned short)(r3 >> 16));
#pragma unroll
    for (int j = 0; j < 8; ++j) {
      acc[j] += bf2f((unsigned short)v0[j]) * w0;
      acc[j] += bf2f((unsigned short)v1[j]) * w1;
      acc[j] += bf2f((unsigned short)v2[j]) * w2;
      acc[j] += bf2f((unsigned short)v3[j]) * w3;
    }
  }
  for (; k < end; ++k) {
    unsigned r0 = es[k];
    short8v v0 = *(const short8v*)(chunk + (size_t)(r0 & 0xFFFF) * 32 + q * 8);
    float w0 = bf2f((unsigned short)(r0 >> 16));
#pragma unroll
    for (int j = 0; j < 8; ++j) acc[j] += bf2f((unsigned short)v0[j]) * w0;
  }

  float* orow = hn + (size_t)node * D + c * 32 + q * 8;
  *(float4*)(orow) = make_float4(acc[0], acc[1], acc[2], acc[3]);
  *(float4*)(orow + 4) = make_float4(acc[4], acc[5], acc[6], acc[7]);
}

// ---------------------------------------------------------------------------
// Bi-interaction via 16x16x32 bf16 MFMA (proven); h read from the CHUNKED
// layout (col>>5 selects chunk; coalescing preserved per 8-thread group).
// ---------------------------------------------------------------------------
__global__ __launch_bounds__(256) void bi_mfma_h16(
    const unsigned short* __restrict__ nf16t, const float* __restrict__ hn,
    const unsigned short* __restrict__ wc, float* __restrict__ out) {
  __shared__ __align__(16) unsigned short lds[2 * 64 * D];  // 32 KiB

  const int tid = threadIdx.x;
  const int lane = tid & 63;
  const int wid = tid >> 6;
  const int base = blockIdx.x * 64;
  const int r16 = lane & 15;
  const int kg = lane >> 4;

  short8v bf[2][2][4];
  {
    const int colbase = wid * 32;
#pragma unroll
    for (int g = 0; g < 2; ++g)
#pragma unroll
      for (int c = 0; c < 2; ++c)
#pragma unroll
        for (int ks = 0; ks < 4; ++ks) {
          int col = colbase + c * 16 + r16;
          int k = ks * 32 + kg * 8;
          bf[g][c][ks] =
              *(const short8v*)(wc + (size_t)g * D * D + (size_t)col * D + k);
        }
  }

#pragma unroll
  for (int p = 0; p < 8; ++p) {
    int flat = p * 1024 + tid * 4;
    int row = flat >> 7;
    int col = flat & 127;
    int node = base + row;
    float hx0 = 0.f, hx1 = 0.f, hx2 = 0.f, hx3 = 0.f;
    float4 nv = make_float4(0.f, 0.f, 0.f, 0.f);
    if (node < N_NODES) {
      const unsigned short* hp =
          nf16t + ((size_t)(col >> 5) * N_NODES + node) * 32 + (col & 31);
      short4v hv = *(const short4v*)hp;
      hx0 = bf2f((unsigned short)hv[0]);
      hx1 = bf2f((unsigned short)hv[1]);
      hx2 = bf2f((unsigned short)hv[2]);
      hx3 = bf2f((unsigned short)hv[3]);
      nv = *(const float4*)(hn + (size_t)node * D + col);
    }
    short4v av, mv;
    av[0] = (short)f2bf(hx0 + nv.x);
    av[1] = (short)f2bf(hx1 + nv.y);
    av[2] = (short)f2bf(hx2 + nv.z);
    av[3] = (short)f2bf(hx3 + nv.w);
    mv[0] = (short)f2bf(hx0 * nv.x);
    mv[1] = (short)f2bf(hx1 * nv.y);
    mv[2] = (short)f2bf(hx2 * nv.z);
    mv[3] = (short)f2bf(hx3 * nv.w);
    int boff = (row * 256 + col * 2) ^ ((row & 7) << 4);
    *(short4v*)((char*)lds + boff) = av;
    *(short4v*)((char*)lds + 16384 + boff) = mv;
  }
  __syncthreads();

  f32x4 acc1[4][2], acc2[4][2];
#pragma unroll
  for (int rt = 0; rt < 4; ++rt)
#pragma unroll
    for (int c = 0; c < 2; ++c) {
      acc1[rt][c] = (f32x4){0.f, 0.f, 0.f, 0.f};
      acc2[rt][c] = (f32x4){0.f, 0.f, 0.f, 0.f};
    }

#pragma unroll
  for (int ks = 0; ks < 4; ++ks) {
#pragma unroll
    for (int rt = 0; rt < 4; ++rt) {
      int row = rt * 16 + r16;
      int boff = (row * 256 + (ks * 32 + kg * 8) * 2) ^ ((row & 7) << 4);
      short8v a1 = *(const short8v*)((const char*)lds + boff);
      short8v a2 = *(const short8v*)((const char*)lds + 16384 + boff);
#pragma unroll
      for (int c = 0; c < 2; ++c) {
        acc1[rt][c] = __builtin_amdgcn_mfma_f32_16x16x32_bf16(
            a1, bf[0][c][ks], acc1[rt][c], 0, 0, 0);
        acc2[rt][c] = __builtin_amdgcn_mfma_f32_16x16x32_bf16(
            a2, bf[1][c][ks], acc2[rt][c], 0, 0, 0);
      }
    }
  }

  // C/D mapping: col = lane&15, row = (lane>>4)*4 + reg.
#pragma unroll
  for (int rt = 0; rt < 4; ++rt) {
#pragma unroll
    for (int c = 0; c < 2; ++c) {
#pragma unroll
      for (int e = 0; e < 4; ++e) {
        int row = rt * 16 + kg * 4 + e;
        int node = base + row;
        if (node < N_NODES) {
          int col = wid * 32 + c * 16 + r16;
          float x1 = acc1[rt][c][e];
          float x2 = acc2[rt][c][e];
          x1 = x1 > 0.f ? x1 : 0.01f * x1;
          x2 = x2 > 0.f ? x2 : 0.01f * x2;
          out[(size_t)node * D + col] = x1 + x2;
        }
      }
    }
  }
}

// ---------------------------------------------------------------------------
// Tier-0 fallback: atomic scatter + VALU GEMM.
// ---------------------------------------------------------------------------
__global__ __launch_bounds__(256) void edge_scatter(
    const float* __restrict__ nfeat, const float* __restrict__ w,
    const int* __restrict__ src, const int* __restrict__ dst,
    float* __restrict__ hn) {
  int tid = blockIdx.x * 256 + threadIdx.x;
  int e = tid >> 5;
  if (e >= N_EDGES) return;
  int q = tid & 31;
  int s = src[e];
  int d = dst[e];
  float we = w[e];
  float4 v = ((const float4*)(nfeat + (size_t)s * D))[q];
  float* drow = hn + (size_t)d * D + q * 4;
  atomicAdd(drow + 0, v.x * we);
  atomicAdd(drow + 1, v.y * we);
  atomicAdd(drow + 2, v.z * we);
  atomicAdd(drow + 3, v.w * we);
}

__global__ __launch_bounds__(256) void bi_inter(
    const float* __restrict__ h, const float* __restrict__ hn,
    const float* __restrict__ W1, const float* __restrict__ W2,
    float* __restrict__ out) {
  int wid = __builtin_amdgcn_readfirstlane(threadIdx.x >> 6);
  int lane = threadIdx.x & 63;
  int node = blockIdx.x * 64 + lane;
  if (node >= N_NODES) return;
  const float4* h4 = (const float4*)(h + (size_t)node * D);
  const float4* n4 = (const float4*)(hn + (size_t)node * D);
  float acc1[32], acc2[32];
#pragma unroll
  for (int j = 0; j < 32; ++j) { acc1[j] = 0.f; acc2[j] = 0.f; }
  const int obase = wid * 32;
  for (int kq = 0; kq < 32; ++kq) {
    float4 hv = h4[kq];
    float4 nv = n4[kq];
    float a0 = hv.x + nv.x, a1 = hv.y + nv.y, a2 = hv.z + nv.z, a3 = hv.w + nv.w;
    float m0 = hv.x * nv.x, m1 = hv.y * nv.y, m2 = hv.z * nv.z, m3 = hv.w * nv.w;
#pragma unroll
    for (int j = 0; j < 32; ++j) {
      int o = obase + j;
      float4 w1 = *(const float4*)(W1 + (size_t)o * D + kq * 4);
      float4 w2 = *(const float4*)(W2 + (size_t)o * D + kq * 4);
      acc1[j] += a0 * w1.x + a1 * w1.y + a2 * w1.z + a3 * w1.w;
      acc2[j] += m0 * w2.x + m1 * w2.y + m2 * w2.z + m3 * w2.w;
    }
  }
  float* orow = out + (size_t)node * D + obase;
#pragma unroll
  for (int j = 0; j < 32; j += 4) {
    float4 r;
    float x;
    x = acc1[j + 0]; x = x > 0.f ? x : 0.01f * x;
    r.x = x; x = acc2[j + 0]; x = x > 0.f ? x : 0.01f * x; r.x += x;
    x = acc1[j + 1]; x = x > 0.f ? x : 0.01f * x;
    r.y = x; x = acc2[j + 1]; x = x > 0.f ? x : 0.01f * x; r.y += x;
    x = acc1[j + 2]; x = x > 0.f ? x : 0.01f * x;
    r.z = x; x = acc2[j + 2]; x = x > 0.f ? x : 0.01f * x; r.z += x;
    x = acc1[j + 3]; x = x > 0.f ? x : 0.01f * x;
    r.w = x; x = acc2[j + 3]; x = x > 0.f ? x : 0.01f * x; r.w += x;
    *(float4*)(orow + j) = r;
  }
}

extern "C" void kernel_launch(void* const* d_in, const int* in_sizes, int n_in,
                              void* d_out, int out_size, void* d_ws, size_t ws_size,
                              hipStream_t stream) {
  const float* nfeat = (const float*)d_in[0];
  const float* w     = (const float*)d_in[1];
  const float* W1    = (const float*)d_in[2];
  const float* W2    = (const float*)d_in[3];
  const int*   src   = (const int*)d_in[4];
  const int*   dst   = (const int*)d_in[5];

  float* hn  = (float*)d_out;
  float* out = (float*)d_out + OUT0_ELEMS;

  // Workspace layout (~16 MB; rank array deleted)
  char* ws = (char*)d_ws;
  size_t off = 0;
  int* cnt = (int*)(ws + off);          off += (size_t)N_NODES * 4;
  int* offs = (int*)(ws + off);         off += (size_t)(N_NODES + 1) * 4;
  int* bsums = (int*)(ws + off);        off += 256 * 4;
  unsigned* es = (unsigned*)(ws + off); off += (size_t)N_EDGES * 4;
  off = (off + 63) & ~(size_t)63;
  unsigned short* wc = (unsigned short*)(ws + off);
  off += (size_t)2 * D * D * 2;
  off = (off + 63) & ~(size_t)63;
  unsigned short* nf16t = (unsigned short*)(ws + off);
  off += (size_t)N_NODES * D * 2;
  size_t full_bytes = off;

  if (ws_size < full_bytes) {
    // Tier 0: atomic scatter + VALU GEMM (correct, slow).
    hipMemsetAsync(hn, 0, (size_t)OUT0_ELEMS * sizeof(float), stream);
    long long threads = (long long)N_EDGES * 32;
    int blocks = (int)((threads + 255) / 256);
    edge_scatter<<<blocks, 256, 0, stream>>>(nfeat, w, src, dst, hn);
    bi_inter<<<(N_NODES + 63) / 64, 256, 0, stream>>>(nfeat, hn, W1, W2, out);
    return;
  }

  conv_all<<<N_NODES * D / 8 / 256, 256, 0, stream>>>(
      nfeat, W1, W2, nf16t, wc, cnt);                               // 3125
  hist4<<<N_EDGES / 4 / 256, 256, 0, stream>>>(dst, cnt);           // 625
  scan_block<<<SCAN_BLOCKS, 256, 0, stream>>>(cnt, cnt, offs, bsums); // 196
  fill_cur<<<N_EDGES / 4 / 256, 256, 0, stream>>>(src, dst, w, cnt, offs,
                                                  bsums, es);       // 625
  gather_chunk<<<4 * GB_BLOCKS_PER_CHUNK, 256, 0, stream>>>(
      nf16t, offs, bsums, es, hn);                                  // 3128
  bi_mfma_h16<<<(N_NODES + 63) / 64, 256, 0, stream>>>(nf16t, hn, wc, out);
}

// Round 15
// 103.322 us; speedup vs baseline: 1.2353x; 1.2353x over previous
//
#include <hip/hip_runtime.h>
#include <hip/hip_bf16.h>

#define N_NODES 50000
#define N_EDGES 640000
#define D 128
#define OUT0_ELEMS (N_NODES * D)
#define SCAN_BLOCKS ((N_NODES + 255) / 256)   // 196

// gather_chunk geometry: 4 column-chunks of 32 cols; 64 nodes/block.
#define GB_NODES 64
#define GB_BLOCKS_PER_CHUNK ((N_NODES + GB_NODES - 1) / GB_NODES)   // 782

typedef __attribute__((ext_vector_type(8))) short short8v;   // 8 bf16
typedef __attribute__((ext_vector_type(4))) short short4v;   // 4 bf16
typedef __attribute__((ext_vector_type(4))) float f32x4;

static __device__ __forceinline__ unsigned short f2bf(float x) {
  __hip_bfloat16 b = __float2bfloat16(x);   // RNE
  return *reinterpret_cast<unsigned short*>(&b);
}
static __device__ __forceinline__ float bf2f(unsigned short u) {
  unsigned x = ((unsigned)u) << 16;
  return __builtin_bit_cast(float, x);
}
// Edge record: (bf16(w) << 16) | src   (src < 50000 < 2^16)
static __device__ __forceinline__ unsigned pack_edge(int s, float wv) {
  return ((unsigned)f2bf(wv) << 16) | (unsigned)s;
}

// ---------------------------------------------------------------------------
// conv_all: nfeat f32->bf16 into the chunked layout nf16t[4][N][32],
// W1/W2 -> bf16, zero cnt.  3125 blocks x 256 thr x 8 elems.  (proven r13)
// ---------------------------------------------------------------------------
__global__ __launch_bounds__(256) void conv_all(
    const float* __restrict__ nfeat, const float* __restrict__ W1,
    const float* __restrict__ W2, unsigned short* __restrict__ nf16t,
    unsigned short* __restrict__ wc, int* __restrict__ cnt) {
  int i = blockIdx.x * 256 + threadIdx.x;
  int base = i * 8;
  float4 a = *(const float4*)(nfeat + base);
  float4 b = *(const float4*)(nfeat + base + 4);
  short8v o;
  o[0] = (short)f2bf(a.x); o[1] = (short)f2bf(a.y);
  o[2] = (short)f2bf(a.z); o[3] = (short)f2bf(a.w);
  o[4] = (short)f2bf(b.x); o[5] = (short)f2bf(b.y);
  o[6] = (short)f2bf(b.z); o[7] = (short)f2bf(b.w);
  // cols [col0, col0+8) all land in chunk col0>>5 (col0 is 8-aligned)
  {
    int node = base >> 7;
    int col0 = base & 127;
    int c = col0 >> 5;
    int within = col0 & 31;
    *(short8v*)(nf16t + ((size_t)c * N_NODES + node) * 32 + within) = o;
  }
  if (i < D * D) {
    wc[i] = f2bf(W1[i]);
    wc[D * D + i] = f2bf(W2[i]);
  }
  if (i < N_NODES) cnt[i] = 0;
}

// ---------------------------------------------------------------------------
// hist + rank: rank[e] = fetch-add(cnt[dst[e]]).  4 edges/thread.
// (proven r13 — returns feed ONE coalesced int4 store; the round-14 variant
// that chained each return into a scattered store cost +24us)
// ---------------------------------------------------------------------------
__global__ __launch_bounds__(256) void hist_rank(
    const int* __restrict__ dst, int* __restrict__ cnt, int* __restrict__ rank) {
  int t = blockIdx.x * 256 + threadIdx.x;
  int e = t * 4;
  if (e >= N_EDGES) return;
  int4 d4 = *(const int4*)(dst + e);
  int4 r4;
  r4.x = atomicAdd(&cnt[d4.x], 1);
  r4.y = atomicAdd(&cnt[d4.y], 1);
  r4.z = atomicAdd(&cnt[d4.z], 1);
  r4.w = atomicAdd(&cnt[d4.w], 1);
  *(int4*)(rank + e) = r4;
}

// ---------------------------------------------------------------------------
// scan_block: per-block (256-node chunk) exclusive scan into offs (block-
// local), block totals into bsums.  Global prefix reconstructed by consumers
// via an LDS scan of the 196 bsums.  (proven)
// ---------------------------------------------------------------------------
__global__ __launch_bounds__(256) void scan_block(
    const int* __restrict__ cnt, int* __restrict__ offs, int* __restrict__ bsums) {
  __shared__ int sdata[256];
  int t = threadIdx.x;
  int i = blockIdx.x * 256 + t;
  int v = (i < N_NODES) ? cnt[i] : 0;
  sdata[t] = v;
  __syncthreads();
#pragma unroll
  for (int off = 1; off < 256; off <<= 1) {
    int x = (t >= off) ? sdata[t - off] : 0;
    __syncthreads();
    sdata[t] += x;
    __syncthreads();
  }
  if (i < N_NODES) offs[i] = sdata[t] - v;   // block-local exclusive
  if (t == 255) bsums[blockIdx.x] = sdata[t];
}

// Inclusive LDS scan of bsums (196 entries); prefix(b) = b ? sincl[b-1] : 0.
static __device__ __forceinline__ void scan_bsums_lds(
    const int* __restrict__ bsums, int* sincl) {
  int t = threadIdx.x;
  int v = (t < SCAN_BLOCKS) ? bsums[t] : 0;
  sincl[t] = v;
  __syncthreads();
#pragma unroll
  for (int off = 1; off < 256; off <<= 1) {
    int x = (t >= off) ? sincl[t - off] : 0;
    __syncthreads();
    sincl[t] += x;
    __syncthreads();
  }
}

// ---------------------------------------------------------------------------
// fill4: atomic-free scatter of packed 4B records; global offset computed
// on the fly as offs_local[d] + prefix(d>>8) + rank.  (proven r13)
// ---------------------------------------------------------------------------
__global__ __launch_bounds__(256) void fill4(
    const int* __restrict__ src, const int* __restrict__ dst,
    const float* __restrict__ w, const int* __restrict__ rank,
    const int* __restrict__ offs, const int* __restrict__ bsums,
    unsigned* __restrict__ es) {
  __shared__ int sincl[256];
  scan_bsums_lds(bsums, sincl);
  int t = blockIdx.x * 256 + threadIdx.x;
  int e = t * 4;
  if (e >= N_EDGES) return;
  int4 d4 = *(const int4*)(dst + e);
  int4 r4 = *(const int4*)(rank + e);
  int4 s4 = *(const int4*)(src + e);
  float4 w4 = *(const float4*)(w + e);
  int p0 = offs[d4.x] + ((d4.x >> 8) ? sincl[(d4.x >> 8) - 1] : 0) + r4.x;
  int p1 = offs[d4.y] + ((d4.y >> 8) ? sincl[(d4.y >> 8) - 1] : 0) + r4.y;
  int p2 = offs[d4.z] + ((d4.z >> 8) ? sincl[(d4.z >> 8) - 1] : 0) + r4.z;
  int p3 = offs[d4.w] + ((d4.w >> 8) ? sincl[(d4.w >> 8) - 1] : 0) + r4.w;
  es[p0] = pack_edge(s4.x, w4.x);
  es[p1] = pack_edge(s4.y, w4.y);
  es[p2] = pack_edge(s4.z, w4.z);
  es[p3] = pack_edge(s4.w, w4.w);
}

// ---------------------------------------------------------------------------
// gather_chunk: XCD-L2-resident gather (proven r13).  chunk = blockIdx&3 ->
// round-robin XCD mapping keeps each 3.2MB feature chunk resident in its
// XCD's 4MB L2.  Plain vectorizable es loads (NT loads cost +24us in r12).
// ---------------------------------------------------------------------------
__global__ __launch_bounds__(256) void gather_chunk(
    const unsigned short* __restrict__ nf16t, const int* __restrict__ offs,
    const int* __restrict__ bsums, const unsigned* __restrict__ es,
    float* __restrict__ hn) {
  __shared__ int sincl[256];
  scan_bsums_lds(bsums, sincl);

  const int c = blockIdx.x & 3;
  const int g = blockIdx.x >> 2;
  const int tid = threadIdx.x;
  const int node = g * GB_NODES + (tid >> 2);
  if (node >= N_NODES) return;
  const int q = tid & 3;

  const unsigned short* chunk = nf16t + (size_t)c * N_NODES * 32;

  int beg = offs[node] + ((node >> 8) ? sincl[(node >> 8) - 1] : 0);
  int end;
  {
    int n1 = node + 1;
    end = (n1 == N_NODES) ? N_EDGES
                          : offs[n1] + ((n1 >> 8) ? sincl[(n1 >> 8) - 1] : 0);
  }

  float acc[8];
#pragma unroll
  for (int j = 0; j < 8; ++j) acc[j] = 0.f;

  int k = beg;
  for (; k + 3 < end; k += 4) {
    unsigned r0 = es[k], r1 = es[k + 1], r2 = es[k + 2], r3 = es[k + 3];
    short8v v0 = *(const short8v*)(chunk + (size_t)(r0 & 0xFFFF) * 32 + q * 8);
    short8v v1 = *(const short8v*)(chunk + (size_t)(r1 & 0xFFFF) * 32 + q * 8);
    short8v v2 = *(const short8v*)(chunk + (size_t)(r2 & 0xFFFF) * 32 + q * 8);
    short8v v3 = *(const short8v*)(chunk + (size_t)(r3 & 0xFFFF) * 32 + q * 8);
    float w0 = bf2f((unsigned short)(r0 >> 16));
    float w1 = bf2f((unsigned short)(r1 >> 16));
    float w2 = bf2f((unsigned short)(r2 >> 16));
    float w3 = bf2f((unsigned short)(r3 >> 16));
#pragma unroll
    for (int j = 0; j < 8; ++j) {
      acc[j] += bf2f((unsigned short)v0[j]) * w0;
      acc[j] += bf2f((unsigned short)v1[j]) * w1;
      acc[j] += bf2f((unsigned short)v2[j]) * w2;
      acc[j] += bf2f((unsigned short)v3[j]) * w3;
    }
  }
  for (; k < end; ++k) {
    unsigned r0 = es[k];
    short8v v0 = *(const short8v*)(chunk + (size_t)(r0 & 0xFFFF) * 32 + q * 8);
    float w0 = bf2f((unsigned short)(r0 >> 16));
#pragma unroll
    for (int j = 0; j < 8; ++j) acc[j] += bf2f((unsigned short)v0[j]) * w0;
  }

  float* orow = hn + (size_t)node * D + c * 32 + q * 8;
  *(float4*)(orow) = make_float4(acc[0], acc[1], acc[2], acc[3]);
  *(float4*)(orow + 4) = make_float4(acc[4], acc[5], acc[6], acc[7]);
}

// ---------------------------------------------------------------------------
// Bi-interaction via 16x16x32 bf16 MFMA (proven); h read from the CHUNKED
// layout (col>>5 selects chunk; coalescing preserved per 8-thread group).
// ---------------------------------------------------------------------------
__global__ __launch_bounds__(256) void bi_mfma_h16(
    const unsigned short* __restrict__ nf16t, const float* __restrict__ hn,
    const unsigned short* __restrict__ wc, float* __restrict__ out) {
  __shared__ __align__(16) unsigned short lds[2 * 64 * D];  // 32 KiB

  const int tid = threadIdx.x;
  const int lane = tid & 63;
  const int wid = tid >> 6;
  const int base = blockIdx.x * 64;
  const int r16 = lane & 15;
  const int kg = lane >> 4;

  short8v bf[2][2][4];
  {
    const int colbase = wid * 32;
#pragma unroll
    for (int g = 0; g < 2; ++g)
#pragma unroll
      for (int c = 0; c < 2; ++c)
#pragma unroll
        for (int ks = 0; ks < 4; ++ks) {
          int col = colbase + c * 16 + r16;
          int k = ks * 32 + kg * 8;
          bf[g][c][ks] =
              *(const short8v*)(wc + (size_t)g * D * D + (size_t)col * D + k);
        }
  }

#pragma unroll
  for (int p = 0; p < 8; ++p) {
    int flat = p * 1024 + tid * 4;
    int row = flat >> 7;
    int col = flat & 127;
    int node = base + row;
    float hx0 = 0.f, hx1 = 0.f, hx2 = 0.f, hx3 = 0.f;
    float4 nv = make_float4(0.f, 0.f, 0.f, 0.f);
    if (node < N_NODES) {
      const unsigned short* hp =
          nf16t + ((size_t)(col >> 5) * N_NODES + node) * 32 + (col & 31);
      short4v hv = *(const short4v*)hp;
      hx0 = bf2f((unsigned short)hv[0]);
      hx1 = bf2f((unsigned short)hv[1]);
      hx2 = bf2f((unsigned short)hv[2]);
      hx3 = bf2f((unsigned short)hv[3]);
      nv = *(const float4*)(hn + (size_t)node * D + col);
    }
    short4v av, mv;
    av[0] = (short)f2bf(hx0 + nv.x);
    av[1] = (short)f2bf(hx1 + nv.y);
    av[2] = (short)f2bf(hx2 + nv.z);
    av[3] = (short)f2bf(hx3 + nv.w);
    mv[0] = (short)f2bf(hx0 * nv.x);
    mv[1] = (short)f2bf(hx1 * nv.y);
    mv[2] = (short)f2bf(hx2 * nv.z);
    mv[3] = (short)f2bf(hx3 * nv.w);
    int boff = (row * 256 + col * 2) ^ ((row & 7) << 4);
    *(short4v*)((char*)lds + boff) = av;
    *(short4v*)((char*)lds + 16384 + boff) = mv;
  }
  __syncthreads();

  f32x4 acc1[4][2], acc2[4][2];
#pragma unroll
  for (int rt = 0; rt < 4; ++rt)
#pragma unroll
    for (int c = 0; c < 2; ++c) {
      acc1[rt][c] = (f32x4){0.f, 0.f, 0.f, 0.f};
      acc2[rt][c] = (f32x4){0.f, 0.f, 0.f, 0.f};
    }

#pragma unroll
  for (int ks = 0; ks < 4; ++ks) {
#pragma unroll
    for (int rt = 0; rt < 4; ++rt) {
      int row = rt * 16 + r16;
      int boff = (row * 256 + (ks * 32 + kg * 8) * 2) ^ ((row & 7) << 4);
      short8v a1 = *(const short8v*)((const char*)lds + boff);
      short8v a2 = *(const short8v*)((const char*)lds + 16384 + boff);
#pragma unroll
      for (int c = 0; c < 2; ++c) {
        acc1[rt][c] = __builtin_amdgcn_mfma_f32_16x16x32_bf16(
            a1, bf[0][c][ks], acc1[rt][c], 0, 0, 0);
        acc2[rt][c] = __builtin_amdgcn_mfma_f32_16x16x32_bf16(
            a2, bf[1][c][ks], acc2[rt][c], 0, 0, 0);
      }
    }
  }

  // C/D mapping: col = lane&15, row = (lane>>4)*4 + reg.
#pragma unroll
  for (int rt = 0; rt < 4; ++rt) {
#pragma unroll
    for (int c = 0; c < 2; ++c) {
#pragma unroll
      for (int e = 0; e < 4; ++e) {
        int row = rt * 16 + kg * 4 + e;
        int node = base + row;
        if (node < N_NODES) {
          int col = wid * 32 + c * 16 + r16;
          float x1 = acc1[rt][c][e];
          float x2 = acc2[rt][c][e];
          x1 = x1 > 0.f ? x1 : 0.01f * x1;
          x2 = x2 > 0.f ? x2 : 0.01f * x2;
          out[(size_t)node * D + col] = x1 + x2;
        }
      }
    }
  }
}

// ---------------------------------------------------------------------------
// Tier-0 fallback: atomic scatter + VALU GEMM.
// ---------------------------------------------------------------------------
__global__ __launch_bounds__(256) void edge_scatter(
    const float* __restrict__ nfeat, const float* __restrict__ w,
    const int* __restrict__ src, const int* __restrict__ dst,
    float* __restrict__ hn) {
  int tid = blockIdx.x * 256 + threadIdx.x;
  int e = tid >> 5;
  if (e >= N_EDGES) return;
  int q = tid & 31;
  int s = src[e];
  int d = dst[e];
  float we = w[e];
  float4 v = ((const float4*)(nfeat + (size_t)s * D))[q];
  float* drow = hn + (size_t)d * D + q * 4;
  atomicAdd(drow + 0, v.x * we);
  atomicAdd(drow + 1, v.y * we);
  atomicAdd(drow + 2, v.z * we);
  atomicAdd(drow + 3, v.w * we);
}

__global__ __launch_bounds__(256) void bi_inter(
    const float* __restrict__ h, const float* __restrict__ hn,
    const float* __restrict__ W1, const float* __restrict__ W2,
    float* __restrict__ out) {
  int wid = __builtin_amdgcn_readfirstlane(threadIdx.x >> 6);
  int lane = threadIdx.x & 63;
  int node = blockIdx.x * 64 + lane;
  if (node >= N_NODES) return;
  const float4* h4 = (const float4*)(h + (size_t)node * D);
  const float4* n4 = (const float4*)(hn + (size_t)node * D);
  float acc1[32], acc2[32];
#pragma unroll
  for (int j = 0; j < 32; ++j) { acc1[j] = 0.f; acc2[j] = 0.f; }
  const int obase = wid * 32;
  for (int kq = 0; kq < 32; ++kq) {
    float4 hv = h4[kq];
    float4 nv = n4[kq];
    float a0 = hv.x + nv.x, a1 = hv.y + nv.y, a2 = hv.z + nv.z, a3 = hv.w + nv.w;
    float m0 = hv.x * nv.x, m1 = hv.y * nv.y, m2 = hv.z * nv.z, m3 = hv.w * nv.w;
#pragma unroll
    for (int j = 0; j < 32; ++j) {
      int o = obase + j;
      float4 w1 = *(const float4*)(W1 + (size_t)o * D + kq * 4);
      float4 w2 = *(const float4*)(W2 + (size_t)o * D + kq * 4);
      acc1[j] += a0 * w1.x + a1 * w1.y + a2 * w1.z + a3 * w1.w;
      acc2[j] += m0 * w2.x + m1 * w2.y + m2 * w2.z + m3 * w2.w;
    }
  }
  float* orow = out + (size_t)node * D + obase;
#pragma unroll
  for (int j = 0; j < 32; j += 4) {
    float4 r;
    float x;
    x = acc1[j + 0]; x = x > 0.f ? x : 0.01f * x;
    r.x = x; x = acc2[j + 0]; x = x > 0.f ? x : 0.01f * x; r.x += x;
    x = acc1[j + 1]; x = x > 0.f ? x : 0.01f * x;
    r.y = x; x = acc2[j + 1]; x = x > 0.f ? x : 0.01f * x; r.y += x;
    x = acc1[j + 2]; x = x > 0.f ? x : 0.01f * x;
    r.z = x; x = acc2[j + 2]; x = x > 0.f ? x : 0.01f * x; r.z += x;
    x = acc1[j + 3]; x = x > 0.f ? x : 0.01f * x;
    r.w = x; x = acc2[j + 3]; x = x > 0.f ? x : 0.01f * x; r.w += x;
    *(float4*)(orow + j) = r;
  }
}

extern "C" void kernel_launch(void* const* d_in, const int* in_sizes, int n_in,
                              void* d_out, int out_size, void* d_ws, size_t ws_size,
                              hipStream_t stream) {
  const float* nfeat = (const float*)d_in[0];
  const float* w     = (const float*)d_in[1];
  const float* W1    = (const float*)d_in[2];
  const float* W2    = (const float*)d_in[3];
  const int*   src   = (const int*)d_in[4];
  const int*   dst   = (const int*)d_in[5];

  float* hn  = (float*)d_out;
  float* out = (float*)d_out + OUT0_ELEMS;

  // Workspace layout (~18.4 MB)
  char* ws = (char*)d_ws;
  size_t off = 0;
  int* cnt = (int*)(ws + off);          off += (size_t)N_NODES * 4;
  int* offs = (int*)(ws + off);         off += (size_t)(N_NODES + 1) * 4;
  int* bsums = (int*)(ws + off);        off += 256 * 4;
  int* rank = (int*)(ws + off);         off += (size_t)N_EDGES * 4;
  unsigned* es = (unsigned*)(ws + off); off += (size_t)N_EDGES * 4;
  off = (off + 63) & ~(size_t)63;
  unsigned short* wc = (unsigned short*)(ws + off);
  off += (size_t)2 * D * D * 2;
  off = (off + 63) & ~(size_t)63;
  unsigned short* nf16t = (unsigned short*)(ws + off);
  off += (size_t)N_NODES * D * 2;
  size_t full_bytes = off;

  if (ws_size < full_bytes) {
    // Tier 0: atomic scatter + VALU GEMM (correct, slow).
    hipMemsetAsync(hn, 0, (size_t)OUT0_ELEMS * sizeof(float), stream);
    long long threads = (long long)N_EDGES * 32;
    int blocks = (int)((threads + 255) / 256);
    edge_scatter<<<blocks, 256, 0, stream>>>(nfeat, w, src, dst, hn);
    bi_inter<<<(N_NODES + 63) / 64, 256, 0, stream>>>(nfeat, hn, W1, W2, out);
    return;
  }

  conv_all<<<N_NODES * D / 8 / 256, 256, 0, stream>>>(
      nfeat, W1, W2, nf16t, wc, cnt);                               // 3125
  hist_rank<<<N_EDGES / 4 / 256, 256, 0, stream>>>(dst, cnt, rank); // 625
  scan_block<<<SCAN_BLOCKS, 256, 0, stream>>>(cnt, offs, bsums);    // 196
  fill4<<<N_EDGES / 4 / 256, 256, 0, stream>>>(src, dst, w, rank, offs,
                                               bsums, es);          // 625
  gather_chunk<<<4 * GB_BLOCKS_PER_CHUNK, 256, 0, stream>>>(
      nf16t, offs, bsums, es, hn);                                  // 3128
  bi_mfma_h16<<<(N_NODES + 63) / 64, 256, 0, stream>>>(nf16t, hn, wc, out);
}